// Round 14
// baseline (360.851 us; speedup 1.0000x reference)
//
#include <hip/hip_runtime.h>
#include <math.h>

#define L 2048
#define D 1024
#define H 16
#define Z 64
#define HZ 1024

typedef __bf16 bf16x8 __attribute__((ext_vector_type(8)));
typedef float f32x4 __attribute__((ext_vector_type(4)));
typedef float f32x16 __attribute__((ext_vector_type(16)));

#if __has_builtin(__builtin_amdgcn_exp2f)
#define EXP2(x) __builtin_amdgcn_exp2f(x)
#else
#define EXP2(x) exp2f(x)
#endif

// ---------------------------------------------------------------------------
// Async global->LDS DMA, 16B per lane (lane i lands at base + i*16).
// ---------------------------------------------------------------------------
__device__ __forceinline__ void async_ld16(const void* g, void* l) {
  __builtin_amdgcn_global_load_lds(
      (const __attribute__((address_space(1))) uint32_t*)(uintptr_t)g,
      (__attribute__((address_space(3))) uint32_t*)(uint32_t)(uintptr_t)l,
      16, 0, 0);
}

// ---------------------------------------------------------------------------
// Fragment-ordered tile staging. 1KB region per (16-row group, 32-col half):
// region = (r>>4)*2 + (cc>>2), slot = (r&15) + (cc&3)*16  (cc = 16B chunk).
// ---------------------------------------------------------------------------
template<int NPIECE>
__device__ __forceinline__ void stage_async(const __bf16* __restrict__ g,
                                            int gstride, char* lds, int tid) {
  const int l = tid & 63, w = tid >> 6;
#pragma unroll
  for (int it = 0; it < NPIECE; ++it) {
    const int region = it * 4 + w;
    const int r = ((region >> 1) << 4) + (l & 15);
    const int c = ((region & 1) << 2) + (l >> 4);
    async_ld16(g + (size_t)r * gstride + c * 8, lds + (region << 10));
  }
}

__device__ __forceinline__ bf16x8 rfrag(const char* lds, int row, int cc) {
  const int region = ((row >> 4) << 1) + (cc >> 2);
  const int slot = (row & 15) + ((cc & 3) << 4);
  return *(const bf16x8*)(lds + region * 1024 + slot * 16);
}

// l-permutation for the transposed kp/qp buffers: within each 16-l group,
// 4-el pieces stored in order [0-3, 8-11, 4-7, 12-15].  (involution)
__device__ __forceinline__ int lperm(int mg) {
  const int off = mg & 15;
  return (mg & ~15) | (((off >> 2) & 1) << 3) | (((off >> 3) & 1) << 2);
}

// ---------------------------------------------------------------------------
// prep: fused cvt (fp32 x -> bf16 xb, blocks 0..4095) + wt (W -> Wb + Wt,
// blocks 4096..4607). Both are independent preprocessing; fusing saves a
// launch gap (R13 measured: launch fusion recovered ~29us total).
// ---------------------------------------------------------------------------
__global__ __launch_bounds__(256) void prep_kernel(
    const float* __restrict__ x, __bf16* __restrict__ xb,
    const float* __restrict__ Wk, const float* __restrict__ Wq,
    __bf16* __restrict__ Wkb, __bf16* __restrict__ Wqb,
    __bf16* __restrict__ Wkt, __bf16* __restrict__ Wqt) {
  __shared__ __bf16 tile[64][65];
  const int bid = blockIdx.x;
  if (bid < 4096) {                    // ---- cvt path (n4 = 4096*256 exact)
    int i = bid * 256 + threadIdx.x;
    float4 v = ((const float4*)x)[i];
    union { __bf16 h[4]; uint2 u; } o;
    o.h[0] = (__bf16)v.x; o.h[1] = (__bf16)v.y;
    o.h[2] = (__bf16)v.z; o.h[3] = (__bf16)v.w;
    ((uint2*)xb)[i] = o.u;
    return;
  }
  const int wb = bid - 4096;           // ---- wt path: 512 blocks
  const int bz = wb >> 8, rem = wb & 255, by = rem >> 4, bx = rem & 15;
  const float* W = bz ? Wq : Wk;
  __bf16* Wb = bz ? Wqb : Wkb;
  __bf16* Wt = bz ? Wqt : Wkt;
  const int r0 = by * 64, c0 = bx * 64;
  const int c = threadIdx.x & 63, rb = threadIdx.x >> 6;
#pragma unroll
  for (int i = 0; i < 16; ++i) {
    int r = rb + i * 4;
    __bf16 v = (__bf16)W[(size_t)(r0 + r) * D + c0 + c];
    tile[r][c] = v;
    Wb[(size_t)(r0 + r) * D + c0 + c] = v;
  }
  __syncthreads();
#pragma unroll
  for (int i = 0; i < 16; ++i) {
    int r = rb + i * 4;
    Wt[(size_t)(c0 + r) * HZ + r0 + c] = tile[c][r];
  }
}

// ---------------------------------------------------------------------------
// proj (R10-proven): kp/qp[bh][l][z] = SCALE * sum_d x*W  (SCALE =
// sqrt(beta*log2e) so grad's S-MFMAs produce log2-domain scores directly);
// kpt/qpt[bh][z][l] = UNSCALED (l-permuted) -> PV operands.
// 128x128 tile, 4 waves x 64x64 quadrant, 32x32x16 MFMA, BK=64,
// async-DMA double-buffered LDS, single barrier per K-iter. R12's 64x128
// + counted-vmcnt port REGRESSED (FETCH 16->24MB from W re-fetch; 50->55us)
// -- keep this structure.
// ---------------------------------------------------------------------------
__global__ __launch_bounds__(256, 2) void proj_kernel(
    const __bf16* __restrict__ xb, const __bf16* __restrict__ Wkb,
    const __bf16* __restrict__ Wqb, const float* __restrict__ beta_p,
    __bf16* __restrict__ kp, __bf16* __restrict__ qp,
    __bf16* __restrict__ kpt, __bf16* __restrict__ qpt) {
  const __bf16* __restrict__ Wb = blockIdx.z ? Wqb : Wkb;
  __bf16* __restrict__ outn = blockIdx.z ? qp : kp;
  __bf16* __restrict__ outt = blockIdx.z ? qpt : kpt;
  const int n0 = blockIdx.x * 128, m0 = blockIdx.y * 128;
  const int tid = threadIdx.x, l = tid & 63, w = tid >> 6;
  const int l31 = l & 31, hi = l >> 5;
  const int mh = w >> 1, nh = w & 1;
  const float ab = beta_p[0] * 1.44269504f;
  const float ssc = sqrtf(fabsf(ab));
  const float sc = blockIdx.z ? ssc : ((ab < 0.f) ? -ssc : ssc);
  __shared__ __align__(16) char sA[2][16384], sB[2][16384];

  f32x16 acc[2][2];
#pragma unroll
  for (int mi = 0; mi < 2; ++mi)
#pragma unroll
    for (int ni = 0; ni < 2; ++ni)
#pragma unroll
      for (int i = 0; i < 16; ++i) acc[mi][ni][i] = 0.f;

  const __bf16* __restrict__ Abase = xb + (size_t)m0 * D;
  const __bf16* __restrict__ Bbase = Wb + (size_t)n0 * D;
  stage_async<4>(Abase, D, sA[0], tid);
  stage_async<4>(Bbase, D, sB[0], tid);
  __syncthreads();

  for (int k = 0; k < 16; ++k) {
    const int cur = k & 1, nxt = cur ^ 1;
    if (k < 15) {
      stage_async<4>(Abase + (k + 1) * 64, D, sA[nxt], tid);
      stage_async<4>(Bbase + (k + 1) * 64, D, sB[nxt], tid);
    }
#pragma unroll
    for (int ks = 0; ks < 4; ++ks) {
      bf16x8 am[2], bn[2];
#pragma unroll
      for (int mi = 0; mi < 2; ++mi)
        am[mi] = rfrag(sA[cur], mh * 64 + mi * 32 + l31, 2 * ks + hi);
#pragma unroll
      for (int ni = 0; ni < 2; ++ni)
        bn[ni] = rfrag(sB[cur], nh * 64 + ni * 32 + l31, 2 * ks + hi);
#pragma unroll
      for (int mi = 0; mi < 2; ++mi)
#pragma unroll
        for (int ni = 0; ni < 2; ++ni)
          acc[mi][ni] = __builtin_amdgcn_mfma_f32_32x32x16_bf16(
              am[mi], bn[ni], acc[mi][ni], 0, 0, 0);
    }
    __syncthreads();
  }

  const int b = m0 >> 11;
  const int h = (n0 >> 6) + nh;
  const size_t bh = (size_t)b * H + h;
#pragma unroll
  for (int mi = 0; mi < 2; ++mi)
#pragma unroll
    for (int ni = 0; ni < 2; ++ni) {
      const int z = ni * 32 + l31;
#pragma unroll
      for (int rg = 0; rg < 4; ++rg) {
        const int mloc = mh * 64 + mi * 32 + 8 * rg + 4 * hi;
        const int mg = (m0 & (L - 1)) + mloc;
        union { __bf16 hh[4]; uint2 u; } pk;
#pragma unroll
        for (int j = 0; j < 4; ++j) {
          const float v = acc[mi][ni][4 * rg + j];
          pk.hh[j] = (__bf16)v;                                 // unscaled -> T
          outn[(bh * L + mg + j) * Z + z] = (__bf16)(v * sc);   // scaled -> S ops
        }
        *(uint2*)(outt + (bh * Z + z) * L + lperm(mg)) = pk.u;
      }
    }
}

// ---------------------------------------------------------------------------
// grad kernel (R10, proven): 32x32x16 MFMA, 1 q-tile (32 rows) per wave,
// 512-block x 4-wave shape. BOTH S and T tiles staged through LDS (R6)
// with triple-buffer + counted-vmcnt barriers (T3/T4). R9/R11 q=64
// widening spilled both times (VGPR pinned at 128) -- do not widen.
// kscale FUSED into the MODE-0 epilogue (R10).
// Scores come out of the S-MFMA already in log2-domain (inputs pre-scaled).
// MODE 0: Gkp[q][z] = -(1/li_q) sum_c 2^S[q][c] * qp[c][z]; lse=ln(li);
//         then kpt *= 1/li along its q-columns.
// MODE 1: Gqp[kq][z] = -sum_q 2^S[q][kq] * kpw[q][z]  (kpw pre-scaled)
// ---------------------------------------------------------------------------
template<int MODE>
__global__ __launch_bounds__(256, 2) void grad_kernel(
    const __bf16* __restrict__ Rg, const __bf16* __restrict__ Sg,
    const __bf16* __restrict__ Tg,
    float* __restrict__ lse, __bf16* __restrict__ Gout,
    __bf16* __restrict__ kscale_t) {
  const int bid = blockIdx.x;
  const int slot = bid >> 3;
  const int bh = (bid & 7) * 4 + (slot >> 4);
  const int qt = slot & 15;
  const int tid = threadIdx.x, l = tid & 63, w = tid >> 6;
  const int l31 = l & 31, hi = l >> 5;
  const int q0 = qt * 128 + w * 32;
  __shared__ __align__(16) char sS[3][8192], sT[3][8192];  // triple-buffered

  // resident operand as 32x32x16 B-fragments: B[n=l31][k=16ks+8hi+j]
  bf16x8 bres[4];
#pragma unroll
  for (int ks = 0; ks < 4; ++ks)
    bres[ks] = *(const bf16x8*)(
        Rg + ((size_t)bh * L + q0 + l31) * Z + ks * 16 + hi * 8);

  f32x16 pv[2];
#pragma unroll
  for (int zt = 0; zt < 2; ++zt)
#pragma unroll
    for (int i = 0; i < 16; ++i) pv[zt][i] = 0.f;
  float li = 0.f;

  const __bf16* __restrict__ Sbase = Sg + (size_t)bh * L * Z;  // + c*Z
  const __bf16* __restrict__ Tbase = Tg + (size_t)bh * Z * L;  // + z*L + c

  // prologue: bres(4) then tiles 0 and 1 for both S and T (8 DMAs).
  // vmcnt(4) waits bres + tile0 (oldest 8), leaves tile1's 4 in flight.
  stage_async<2>(Sbase, Z, sS[0], tid);
  stage_async<2>(Tbase, L, sT[0], tid);
  stage_async<2>(Sbase + (size_t)64 * Z, Z, sS[1], tid);
  stage_async<2>(Tbase + 64, L, sT[1], tid);
  asm volatile("s_waitcnt vmcnt(4)" ::: "memory");
  __builtin_amdgcn_s_barrier();

  const char* s0 = sS[0]; const char* s1 = sS[1]; char* s2 = sS[2];
  const char* t0 = sT[0]; const char* t1 = sT[1]; char* t2 = sT[2];

  for (int kt = 0; kt < 32; ++kt) {
    // fragments for the current tile (DMA'd >= 1 full iteration ago)
    bf16x8 av[8], bt[8];
#pragma unroll
    for (int ks = 0; ks < 4; ++ks) {
      av[ks]     = rfrag(s0, l31,      2 * ks + hi);
      av[4 + ks] = rfrag(s0, 32 + l31, 2 * ks + hi);
      bt[2 * ks]     = rfrag(t0, l31,      2 * ks + hi);
      bt[2 * ks + 1] = rfrag(t0, 32 + l31, 2 * ks + hi);
    }
    // DMA tile kt+2 into the buffers freed at the end of iter kt-1
    if (kt < 30) {
      stage_async<2>(Sbase + (size_t)(kt + 2) * 64 * Z, Z, s2, tid);
      stage_async<2>(Tbase + (kt + 2) * 64, L, t2, tid);
    }
    // St[c][q] = sum_z streamed[c][z] * resident[q][z]  (log2-domain scores)
    f32x16 st[2];
#pragma unroll
    for (int i = 0; i < 16; ++i) { st[0][i] = 0.f; st[1][i] = 0.f; }
    __builtin_amdgcn_s_setprio(1);
#pragma unroll
    for (int ks = 0; ks < 4; ++ks) {
      st[0] = __builtin_amdgcn_mfma_f32_32x32x16_bf16(av[ks], bres[ks], st[0], 0, 0, 0);
      st[1] = __builtin_amdgcn_mfma_f32_32x32x16_bf16(av[4 + ks], bres[ks], st[1], 0, 0, 0);
    }
    __builtin_amdgcn_s_setprio(0);
    // P = 2^St (fixed max = 0), packed as PV A-frags
    uint32_t P32[2][8];
    float lsn = 0.f;
#pragma unroll
    for (int nt = 0; nt < 2; ++nt)
#pragma unroll
      for (int i = 0; i < 8; ++i) {
        float e0 = EXP2(st[nt][2 * i]);
        float e1 = EXP2(st[nt][2 * i + 1]);
        if (MODE == 0) lsn += e0 + e1;
        union { __bf16 hh[2]; uint32_t u; } pk;
        pk.hh[0] = (__bf16)e0; pk.hh[1] = (__bf16)e1;
        P32[nt][i] = pk.u;
      }
    if (MODE == 0) li += lsn;
    // PV: D[q][z] += P[q][c] * T[c][z]
    __builtin_amdgcn_s_setprio(1);
#pragma unroll
    for (int kc = 0; kc < 4; ++kc) {
      union { uint32_t u[4]; bf16x8 v; } a;
#pragma unroll
      for (int i = 0; i < 4; ++i) a.u[i] = P32[kc >> 1][4 * (kc & 1) + i];
      pv[0] = __builtin_amdgcn_mfma_f32_32x32x16_bf16(a.v, bt[2 * kc], pv[0], 0, 0, 0);
      pv[1] = __builtin_amdgcn_mfma_f32_32x32x16_bf16(a.v, bt[2 * kc + 1], pv[1], 0, 0, 0);
    }
    __builtin_amdgcn_s_setprio(0);
    // counted-vmcnt barrier: wait ONLY the previous iteration's 4 DMAs
    // (outstanding = prev 4 + this iter's 4 = 8 -> vmcnt(4)).
    if (kt < 30) {
      asm volatile("s_waitcnt vmcnt(4)" ::: "memory");
      __builtin_amdgcn_s_barrier();
    } else if (kt == 30) {           // nothing issued this iter: wait last 4
      asm volatile("s_waitcnt vmcnt(0)" ::: "memory");
      __builtin_amdgcn_s_barrier();
    }                                // kt==31: nothing left to stage
    const char* x;
    x = s0; s0 = s1; s1 = s2; s2 = (char*)x;
    x = t0; t0 = t1; t1 = t2; t2 = (char*)x;
  }

  if (MODE == 0) li += __shfl_xor(li, 32);
  const int b = bh >> 4, head = bh & (H - 1);
#pragma unroll
  for (int r = 0; r < 16; ++r) {
    const int qoff = (r & 3) + 8 * (r >> 2) + 4 * hi;   // C-layout row
    float scl = 1.f;
    if (MODE == 0)
      scl = 1.f / __int_as_float(
                __builtin_amdgcn_ds_bpermute(4 * qoff, __float_as_int(li)));
    const size_t orow = ((size_t)b * L + q0 + qoff) * HZ + head * Z;
    Gout[orow + l31]      = (__bf16)(-pv[0][r] * scl);
    Gout[orow + 32 + l31] = (__bf16)(-pv[1][r] * scl);
  }
  if (MODE == 0) {
    if (hi == 0)
      lse[(size_t)bh * L + q0 + l31] = __logf(li);
    // ---- fused kscale: kpt[bh][z][q0..q0+32) *= 1/li (this wave's q-range).
    // lane l: piece = l&7 (4 stored bf16 at offset 4*piece), z = l>>3 (+8/pass).
    // Stored piece at pos4 holds true l-positions lperm(pos4)+{0..3}; the
    // needed 1/li values live in lanes lperm(pos4)+j (all lanes have li).
    const float rli = 1.f / li;
    const int pos4 = (l & 7) * 4;
    const int lb = lperm(pos4);
    float sf[4];
#pragma unroll
    for (int j = 0; j < 4; ++j)
      sf[j] = __int_as_float(
          __builtin_amdgcn_ds_bpermute(4 * (lb + j), __float_as_int(rli)));
    __bf16* krow = kscale_t + ((size_t)bh * Z + (l >> 3)) * L + q0 + pos4;
#pragma unroll
    for (int pass = 0; pass < 8; ++pass) {
      union { __bf16 hh[4]; uint2 u; } v;
      v.u = *(uint2*)krow;
      v.hh[0] = (__bf16)((float)v.hh[0] * sf[0]);
      v.hh[1] = (__bf16)((float)v.hh[1] * sf[1]);
      v.hh[2] = (__bf16)((float)v.hh[2] * sf[2]);
      v.hh[3] = (__bf16)((float)v.hh[3] * sf[3]);
      *(uint2*)krow = v.u;
      krow += (size_t)8 * L;
    }
  }
}

// ---------------------------------------------------------------------------
// gx + energy fused: blocks 0..511 compute gx[m][d] = sum_hz Gkp*Wk + Gqp*Wq
// (64x128 tile, 2/CU, XCD-aware m-slab decode, triple-buffer + counted
// vmcnt -- R8's proven structure); blocks 512..513 compute
// en[b] = -(1/beta) * sum_{h,q} lse[b,h,q] (lse ready: grad<0> precedes).
// R14 fix: the energy path uses ONE WAVE + shfl only -- NO __shared__.
// R13's wsum[4] pushed static LDS 73728->74240; at 74240 the 2-blocks/CU
// budget (measured limit: 2x73728=147456 B exactly) is exceeded -> gx fell
// to 1 block/CU (Occupancy 18.6->12.1, dur 49->77us). LDS must stay 73728.
// ---------------------------------------------------------------------------
__global__ __launch_bounds__(256, 2) void gx_kernel(
    const __bf16* __restrict__ Gkp, const __bf16* __restrict__ Gqp,
    const __bf16* __restrict__ Wkt, const __bf16* __restrict__ Wqt,
    const float* __restrict__ lse_ws, const float* __restrict__ beta_p,
    float* __restrict__ out) {
  const int bid = blockIdx.x;                  // 0..513
  if (bid >= 512) {                            // ---- energy path (no LDS!)
    if (threadIdx.x >= 64) return;
    const int b = bid - 512;
    const float* p = lse_ws + (size_t)b * H * L;
    float sum = 0.f;
    for (int i = threadIdx.x; i < H * L; i += 64) sum += p[i];
#pragma unroll
    for (int off = 1; off < 64; off <<= 1) sum += __shfl_xor(sum, off, 64);
    if (threadIdx.x == 0) out[b] = -sum / beta_p[0];
    return;
  }
  float* __restrict__ gx = out + 2;
  const int xcd = bid & 7;                     // dispatch round-robin -> XCD
  const int nt_ = (bid >> 3) & 7;              // 8 n-tiles of 128
  const int mg = bid >> 6;                     // 8 m-tiles within the group
  const int m0 = (xcd * 8 + mg) * 64;          // XCD-local 512-row A-slab
  const int n0 = nt_ * 128;
  const int tid = threadIdx.x, l = tid & 63, w = tid >> 6;
  const int l31 = l & 31, hi = l >> 5;
  const int mh = w >> 1, nh = w & 1;           // 2 m-halves x 2 n-halves
  __shared__ __align__(16) char sA[3][8192], sB[3][16384];

  f32x16 acc[2];
#pragma unroll
  for (int ni = 0; ni < 2; ++ni)
#pragma unroll
    for (int i = 0; i < 16; ++i) acc[ni][i] = 0.f;

  // K-tile source helper: kk in [0,32), first 16 from Gkp/Wkt, rest Gqp/Wqt
  auto stageK = [&](int kn, char* a, char* b) {
    const __bf16* __restrict__ An = (kn < 16 ? Gkp : Gqp);
    const __bf16* __restrict__ Bn = (kn < 16 ? Wkt : Wqt);
    const int k0 = (kn & 15) * 64;
    stage_async<2>(An + (size_t)m0 * HZ + k0, HZ, a, tid);
    stage_async<4>(Bn + (size_t)n0 * HZ + k0, HZ, b, tid);
  };

  // prologue: tiles 0 and 1 (12 DMAs); wait tile 0 only (oldest 6).
  stageK(0, sA[0], sB[0]);
  stageK(1, sA[1], sB[1]);
  asm volatile("s_waitcnt vmcnt(6)" ::: "memory");
  __builtin_amdgcn_s_barrier();

  const char* a0 = sA[0]; const char* a1 = sA[1]; char* a2 = sA[2];
  const char* b0 = sB[0]; const char* b1 = sB[1]; char* b2 = sB[2];

  for (int kk = 0; kk < 32; ++kk) {
    // DMA tile kk+2 into the buffers freed at the end of iter kk-1
    if (kk < 30) stageK(kk + 2, a2, b2);
#pragma unroll
    for (int ks = 0; ks < 4; ++ks) {
      bf16x8 am, bn[2];
      am = rfrag(a0, mh * 32 + l31, 2 * ks + hi);
#pragma unroll
      for (int ni = 0; ni < 2; ++ni)
        bn[ni] = rfrag(b0, nh * 64 + ni * 32 + l31, 2 * ks + hi);
      __builtin_amdgcn_s_setprio(1);
#pragma unroll
      for (int ni = 0; ni < 2; ++ni)
        acc[ni] = __builtin_amdgcn_mfma_f32_32x32x16_bf16(
            am, bn[ni], acc[ni], 0, 0, 0);
      __builtin_amdgcn_s_setprio(0);
    }
    // counted-vmcnt barrier: wait ONLY the previous iteration's 6 DMAs
    if (kk < 30) {
      asm volatile("s_waitcnt vmcnt(6)" ::: "memory");
      __builtin_amdgcn_s_barrier();
    } else if (kk == 30) {
      asm volatile("s_waitcnt vmcnt(0)" ::: "memory");
      __builtin_amdgcn_s_barrier();
    }
    const char* x;
    x = a0; a0 = a1; a1 = a2; a2 = (char*)x;
    x = b0; b0 = b1; b1 = b2; b2 = (char*)x;
  }
#pragma unroll
  for (int ni = 0; ni < 2; ++ni) {
    const int n = n0 + nh * 64 + ni * 32 + l31;
#pragma unroll
    for (int r = 0; r < 16; ++r) {
      const int m = m0 + mh * 32 + (r & 3) + 8 * (r >> 2) + 4 * hi;
      gx[(size_t)m * D + n] = acc[ni][r];
    }
  }
}

// ---------------------------------------------------------------------------
extern "C" void kernel_launch(void* const* d_in, const int* in_sizes, int n_in,
                              void* d_out, int out_size, void* d_ws, size_t ws_size,
                              hipStream_t stream) {
  const float* x    = (const float*)d_in[0];
  const float* Wq   = (const float*)d_in[1];
  const float* Wk   = (const float*)d_in[2];
  const float* beta = (const float*)d_in[3];
  float* out = (float*)d_out;

  char* ws = (char*)d_ws;
  __bf16* xb  = (__bf16*)(ws);                         // 8 MB
  __bf16* Wkb = (__bf16*)(ws + (8ull  << 20));         // 2 MB
  __bf16* Wqb = (__bf16*)(ws + (10ull << 20));         // 2 MB
  __bf16* Wkt = (__bf16*)(ws + (12ull << 20));         // 2 MB
  __bf16* Wqt = (__bf16*)(ws + (14ull << 20));         // 2 MB
  __bf16* kp  = (__bf16*)(ws + (16ull << 20));         // 8 MB (scaled)
  __bf16* qp  = (__bf16*)(ws + (24ull << 20));         // 8 MB (scaled)
  __bf16* kpt = (__bf16*)(ws + (32ull << 20));         // 8 MB (l-perm, unscaled)
  __bf16* qpt = (__bf16*)(ws + (40ull << 20));         // 8 MB (l-perm, unscaled)
  __bf16* Gkp = (__bf16*)(ws + (48ull << 20));         // 8 MB
  __bf16* Gqp = (__bf16*)(ws + (56ull << 20));         // 8 MB
  float*  lse = (float*)(ws + (64ull << 20));          // 256 KB

  prep_kernel<<<4608, 256, 0, stream>>>(x, xb, Wk, Wq, Wkb, Wqb, Wkt, Wqt);
  proj_kernel<<<dim3(8, 32, 2), 256, 0, stream>>>(xb, Wkb, Wqb, beta, kp, qp, kpt, qpt);
  grad_kernel<0><<<512, 256, 0, stream>>>(kp, qp, qpt, lse, Gkp, kpt);
  grad_kernel<1><<<512, 256, 0, stream>>>(qp, kp, kpt, lse, Gqp, kpt);
  gx_kernel<<<514, 256, 0, stream>>>(Gkp, Gqp, Wkt, Wqt, lse, beta, out);
}

// Round 15
// 250.154 us; speedup vs baseline: 1.4425x; 1.4425x over previous
//
#include <hip/hip_runtime.h>
#include <math.h>

#define L 2048
#define D 1024
#define H 16
#define Z 64
#define HZ 1024

typedef __bf16 bf16x8 __attribute__((ext_vector_type(8)));
typedef float f32x4 __attribute__((ext_vector_type(4)));
typedef float f32x16 __attribute__((ext_vector_type(16)));

#if __has_builtin(__builtin_amdgcn_exp2f)
#define EXP2(x) __builtin_amdgcn_exp2f(x)
#else
#define EXP2(x) exp2f(x)
#endif

// ---------------------------------------------------------------------------
// Async global->LDS DMA, 16B per lane (lane i lands at base + i*16).
// ---------------------------------------------------------------------------
__device__ __forceinline__ void async_ld16(const void* g, void* l) {
  __builtin_amdgcn_global_load_lds(
      (const __attribute__((address_space(1))) uint32_t*)(uintptr_t)g,
      (__attribute__((address_space(3))) uint32_t*)(uint32_t)(uintptr_t)l,
      16, 0, 0);
}

// ---------------------------------------------------------------------------
// Fragment-ordered tile staging. 1KB region per (16-row group, 32-col half):
// region = (r>>4)*2 + (cc>>2), slot = (r&15) + (cc&3)*16  (cc = 16B chunk).
// ---------------------------------------------------------------------------
template<int NPIECE>
__device__ __forceinline__ void stage_async(const __bf16* __restrict__ g,
                                            int gstride, char* lds, int tid) {
  const int l = tid & 63, w = tid >> 6;
#pragma unroll
  for (int it = 0; it < NPIECE; ++it) {
    const int region = it * 4 + w;
    const int r = ((region >> 1) << 4) + (l & 15);
    const int c = ((region & 1) << 2) + (l >> 4);
    async_ld16(g + (size_t)r * gstride + c * 8, lds + (region << 10));
  }
}

__device__ __forceinline__ bf16x8 rfrag(const char* lds, int row, int cc) {
  const int region = ((row >> 4) << 1) + (cc >> 2);
  const int slot = (row & 15) + ((cc & 3) << 4);
  return *(const bf16x8*)(lds + region * 1024 + slot * 16);
}

// l-permutation for the transposed kp/qp buffers: within each 16-l group,
// 4-el pieces stored in order [0-3, 8-11, 4-7, 12-15].  (involution)
__device__ __forceinline__ int lperm(int mg) {
  const int off = mg & 15;
  return (mg & ~15) | (((off >> 2) & 1) << 3) | (((off >> 3) & 1) << 2);
}

// ---------------------------------------------------------------------------
// prep: fused cvt (fp32 x -> bf16 xb, blocks 0..4095) + wt (W -> Wb + Wt,
// blocks 4096..4607). Both are independent preprocessing; fusing saves a
// launch gap (R13 measured: launch fusion recovered ~29us total).
// ---------------------------------------------------------------------------
__global__ __launch_bounds__(256) void prep_kernel(
    const float* __restrict__ x, __bf16* __restrict__ xb,
    const float* __restrict__ Wk, const float* __restrict__ Wq,
    __bf16* __restrict__ Wkb, __bf16* __restrict__ Wqb,
    __bf16* __restrict__ Wkt, __bf16* __restrict__ Wqt) {
  __shared__ __bf16 tile[64][65];
  const int bid = blockIdx.x;
  if (bid < 4096) {                    // ---- cvt path (n4 = 4096*256 exact)
    int i = bid * 256 + threadIdx.x;
    float4 v = ((const float4*)x)[i];
    union { __bf16 h[4]; uint2 u; } o;
    o.h[0] = (__bf16)v.x; o.h[1] = (__bf16)v.y;
    o.h[2] = (__bf16)v.z; o.h[3] = (__bf16)v.w;
    ((uint2*)xb)[i] = o.u;
    return;
  }
  const int wb = bid - 4096;           // ---- wt path: 512 blocks
  const int bz = wb >> 8, rem = wb & 255, by = rem >> 4, bx = rem & 15;
  const float* W = bz ? Wq : Wk;
  __bf16* Wb = bz ? Wqb : Wkb;
  __bf16* Wt = bz ? Wqt : Wkt;
  const int r0 = by * 64, c0 = bx * 64;
  const int c = threadIdx.x & 63, rb = threadIdx.x >> 6;
#pragma unroll
  for (int i = 0; i < 16; ++i) {
    int r = rb + i * 4;
    __bf16 v = (__bf16)W[(size_t)(r0 + r) * D + c0 + c];
    tile[r][c] = v;
    Wb[(size_t)(r0 + r) * D + c0 + c] = v;
  }
  __syncthreads();
#pragma unroll
  for (int i = 0; i < 16; ++i) {
    int r = rb + i * 4;
    Wt[(size_t)(c0 + r) * HZ + r0 + c] = tile[c][r];
  }
}

// ---------------------------------------------------------------------------
// proj (R10-proven): kp/qp[bh][l][z] = SCALE * sum_d x*W  (SCALE =
// sqrt(beta*log2e) so grad's S-MFMAs produce log2-domain scores directly);
// kpt/qpt[bh][z][l] = UNSCALED (l-permuted) -> PV operands.
// 128x128 tile, 4 waves x 64x64 quadrant, 32x32x16 MFMA, BK=64,
// async-DMA double-buffered LDS, single barrier per K-iter.
// ---------------------------------------------------------------------------
__global__ __launch_bounds__(256, 2) void proj_kernel(
    const __bf16* __restrict__ xb, const __bf16* __restrict__ Wkb,
    const __bf16* __restrict__ Wqb, const float* __restrict__ beta_p,
    __bf16* __restrict__ kp, __bf16* __restrict__ qp,
    __bf16* __restrict__ kpt, __bf16* __restrict__ qpt) {
  const __bf16* __restrict__ Wb = blockIdx.z ? Wqb : Wkb;
  __bf16* __restrict__ outn = blockIdx.z ? qp : kp;
  __bf16* __restrict__ outt = blockIdx.z ? qpt : kpt;
  const int n0 = blockIdx.x * 128, m0 = blockIdx.y * 128;
  const int tid = threadIdx.x, l = tid & 63, w = tid >> 6;
  const int l31 = l & 31, hi = l >> 5;
  const int mh = w >> 1, nh = w & 1;
  const float ab = beta_p[0] * 1.44269504f;
  const float ssc = sqrtf(fabsf(ab));
  const float sc = blockIdx.z ? ssc : ((ab < 0.f) ? -ssc : ssc);
  __shared__ __align__(16) char sA[2][16384], sB[2][16384];

  f32x16 acc[2][2];
#pragma unroll
  for (int mi = 0; mi < 2; ++mi)
#pragma unroll
    for (int ni = 0; ni < 2; ++ni)
#pragma unroll
      for (int i = 0; i < 16; ++i) acc[mi][ni][i] = 0.f;

  const __bf16* __restrict__ Abase = xb + (size_t)m0 * D;
  const __bf16* __restrict__ Bbase = Wb + (size_t)n0 * D;
  stage_async<4>(Abase, D, sA[0], tid);
  stage_async<4>(Bbase, D, sB[0], tid);
  __syncthreads();

  for (int k = 0; k < 16; ++k) {
    const int cur = k & 1, nxt = cur ^ 1;
    if (k < 15) {
      stage_async<4>(Abase + (k + 1) * 64, D, sA[nxt], tid);
      stage_async<4>(Bbase + (k + 1) * 64, D, sB[nxt], tid);
    }
#pragma unroll
    for (int ks = 0; ks < 4; ++ks) {
      bf16x8 am[2], bn[2];
#pragma unroll
      for (int mi = 0; mi < 2; ++mi)
        am[mi] = rfrag(sA[cur], mh * 64 + mi * 32 + l31, 2 * ks + hi);
#pragma unroll
      for (int ni = 0; ni < 2; ++ni)
        bn[ni] = rfrag(sB[cur], nh * 64 + ni * 32 + l31, 2 * ks + hi);
#pragma unroll
      for (int mi = 0; mi < 2; ++mi)
#pragma unroll
        for (int ni = 0; ni < 2; ++ni)
          acc[mi][ni] = __builtin_amdgcn_mfma_f32_32x32x16_bf16(
              am[mi], bn[ni], acc[mi][ni], 0, 0, 0);
    }
    __syncthreads();
  }

  const int b = m0 >> 11;
  const int h = (n0 >> 6) + nh;
  const size_t bh = (size_t)b * H + h;
#pragma unroll
  for (int mi = 0; mi < 2; ++mi)
#pragma unroll
    for (int ni = 0; ni < 2; ++ni) {
      const int z = ni * 32 + l31;
#pragma unroll
      for (int rg = 0; rg < 4; ++rg) {
        const int mloc = mh * 64 + mi * 32 + 8 * rg + 4 * hi;
        const int mg = (m0 & (L - 1)) + mloc;
        union { __bf16 hh[4]; uint2 u; } pk;
#pragma unroll
        for (int j = 0; j < 4; ++j) {
          const float v = acc[mi][ni][4 * rg + j];
          pk.hh[j] = (__bf16)v;                                 // unscaled -> T
          outn[(bh * L + mg + j) * Z + z] = (__bf16)(v * sc);   // scaled -> S ops
        }
        *(uint2*)(outt + (bh * Z + z) * L + lperm(mg)) = pk.u;
      }
    }
}

// ---------------------------------------------------------------------------
// grad kernel (R10, proven): 32x32x16 MFMA, 1 q-tile (32 rows) per wave,
// 512-block x 4-wave shape. BOTH S and T tiles staged through LDS (R6)
// with triple-buffer + counted-vmcnt barriers (T3/T4). R9/R11 q=64
// widening spilled both times (VGPR pinned at 128) -- do not widen.
// kscale FUSED into the MODE-0 epilogue (R10).
// Scores come out of the S-MFMA already in log2-domain (inputs pre-scaled).
// MODE 0: Gkp[q][z] = -(1/li_q) sum_c 2^S[q][c] * qp[c][z]; lse=ln(li);
//         then kpt *= 1/li along its q-columns.
// MODE 1: Gqp[kq][z] = -sum_q 2^S[q][kq] * kpw[q][z]  (kpw pre-scaled)
// ---------------------------------------------------------------------------
template<int MODE>
__global__ __launch_bounds__(256, 2) void grad_kernel(
    const __bf16* __restrict__ Rg, const __bf16* __restrict__ Sg,
    const __bf16* __restrict__ Tg,
    float* __restrict__ lse, __bf16* __restrict__ Gout,
    __bf16* __restrict__ kscale_t) {
  const int bid = blockIdx.x;
  const int slot = bid >> 3;
  const int bh = (bid & 7) * 4 + (slot >> 4);
  const int qt = slot & 15;
  const int tid = threadIdx.x, l = tid & 63, w = tid >> 6;
  const int l31 = l & 31, hi = l >> 5;
  const int q0 = qt * 128 + w * 32;
  __shared__ __align__(16) char sS[3][8192], sT[3][8192];  // triple-buffered

  // resident operand as 32x32x16 B-fragments: B[n=l31][k=16ks+8hi+j]
  bf16x8 bres[4];
#pragma unroll
  for (int ks = 0; ks < 4; ++ks)
    bres[ks] = *(const bf16x8*)(
        Rg + ((size_t)bh * L + q0 + l31) * Z + ks * 16 + hi * 8);

  f32x16 pv[2];
#pragma unroll
  for (int zt = 0; zt < 2; ++zt)
#pragma unroll
    for (int i = 0; i < 16; ++i) pv[zt][i] = 0.f;
  float li = 0.f;

  const __bf16* __restrict__ Sbase = Sg + (size_t)bh * L * Z;  // + c*Z
  const __bf16* __restrict__ Tbase = Tg + (size_t)bh * Z * L;  // + z*L + c

  // prologue: bres(4) then tiles 0 and 1 for both S and T (8 DMAs).
  // vmcnt(4) waits bres + tile0 (oldest 8), leaves tile1's 4 in flight.
  stage_async<2>(Sbase, Z, sS[0], tid);
  stage_async<2>(Tbase, L, sT[0], tid);
  stage_async<2>(Sbase + (size_t)64 * Z, Z, sS[1], tid);
  stage_async<2>(Tbase + 64, L, sT[1], tid);
  asm volatile("s_waitcnt vmcnt(4)" ::: "memory");
  __builtin_amdgcn_s_barrier();

  const char* s0 = sS[0]; const char* s1 = sS[1]; char* s2 = sS[2];
  const char* t0 = sT[0]; const char* t1 = sT[1]; char* t2 = sT[2];

  for (int kt = 0; kt < 32; ++kt) {
    // fragments for the current tile (DMA'd >= 1 full iteration ago)
    bf16x8 av[8], bt[8];
#pragma unroll
    for (int ks = 0; ks < 4; ++ks) {
      av[ks]     = rfrag(s0, l31,      2 * ks + hi);
      av[4 + ks] = rfrag(s0, 32 + l31, 2 * ks + hi);
      bt[2 * ks]     = rfrag(t0, l31,      2 * ks + hi);
      bt[2 * ks + 1] = rfrag(t0, 32 + l31, 2 * ks + hi);
    }
    // DMA tile kt+2 into the buffers freed at the end of iter kt-1
    if (kt < 30) {
      stage_async<2>(Sbase + (size_t)(kt + 2) * 64 * Z, Z, s2, tid);
      stage_async<2>(Tbase + (kt + 2) * 64, L, t2, tid);
    }
    // St[c][q] = sum_z streamed[c][z] * resident[q][z]  (log2-domain scores)
    f32x16 st[2];
#pragma unroll
    for (int i = 0; i < 16; ++i) { st[0][i] = 0.f; st[1][i] = 0.f; }
    __builtin_amdgcn_s_setprio(1);
#pragma unroll
    for (int ks = 0; ks < 4; ++ks) {
      st[0] = __builtin_amdgcn_mfma_f32_32x32x16_bf16(av[ks], bres[ks], st[0], 0, 0, 0);
      st[1] = __builtin_amdgcn_mfma_f32_32x32x16_bf16(av[4 + ks], bres[ks], st[1], 0, 0, 0);
    }
    __builtin_amdgcn_s_setprio(0);
    // P = 2^St (fixed max = 0), packed as PV A-frags
    uint32_t P32[2][8];
    float lsn = 0.f;
#pragma unroll
    for (int nt = 0; nt < 2; ++nt)
#pragma unroll
      for (int i = 0; i < 8; ++i) {
        float e0 = EXP2(st[nt][2 * i]);
        float e1 = EXP2(st[nt][2 * i + 1]);
        if (MODE == 0) lsn += e0 + e1;
        union { __bf16 hh[2]; uint32_t u; } pk;
        pk.hh[0] = (__bf16)e0; pk.hh[1] = (__bf16)e1;
        P32[nt][i] = pk.u;
      }
    if (MODE == 0) li += lsn;
    // PV: D[q][z] += P[q][c] * T[c][z]
    __builtin_amdgcn_s_setprio(1);
#pragma unroll
    for (int kc = 0; kc < 4; ++kc) {
      union { uint32_t u[4]; bf16x8 v; } a;
#pragma unroll
      for (int i = 0; i < 4; ++i) a.u[i] = P32[kc >> 1][4 * (kc & 1) + i];
      pv[0] = __builtin_amdgcn_mfma_f32_32x32x16_bf16(a.v, bt[2 * kc], pv[0], 0, 0, 0);
      pv[1] = __builtin_amdgcn_mfma_f32_32x32x16_bf16(a.v, bt[2 * kc + 1], pv[1], 0, 0, 0);
    }
    __builtin_amdgcn_s_setprio(0);
    // counted-vmcnt barrier: wait ONLY the previous iteration's 4 DMAs
    // (outstanding = prev 4 + this iter's 4 = 8 -> vmcnt(4)).
    if (kt < 30) {
      asm volatile("s_waitcnt vmcnt(4)" ::: "memory");
      __builtin_amdgcn_s_barrier();
    } else if (kt == 30) {           // nothing issued this iter: wait last 4
      asm volatile("s_waitcnt vmcnt(0)" ::: "memory");
      __builtin_amdgcn_s_barrier();
    }                                // kt==31: nothing left to stage
    const char* x;
    x = s0; s0 = s1; s1 = s2; s2 = (char*)x;
    x = t0; t0 = t1; t1 = t2; t2 = (char*)x;
  }

  if (MODE == 0) li += __shfl_xor(li, 32);
  const int b = bh >> 4, head = bh & (H - 1);
#pragma unroll
  for (int r = 0; r < 16; ++r) {
    const int qoff = (r & 3) + 8 * (r >> 2) + 4 * hi;   // C-layout row
    float scl = 1.f;
    if (MODE == 0)
      scl = 1.f / __int_as_float(
                __builtin_amdgcn_ds_bpermute(4 * qoff, __float_as_int(li)));
    const size_t orow = ((size_t)b * L + q0 + qoff) * HZ + head * Z;
    Gout[orow + l31]      = (__bf16)(-pv[0][r] * scl);
    Gout[orow + 32 + l31] = (__bf16)(-pv[1][r] * scl);
  }
  if (MODE == 0) {
    if (hi == 0)
      lse[(size_t)bh * L + q0 + l31] = __logf(li);
    // ---- fused kscale: kpt[bh][z][q0..q0+32) *= 1/li (this wave's q-range).
    // lane l: piece = l&7 (4 stored bf16 at offset 4*piece), z = l>>3 (+8/pass).
    // Stored piece at pos4 holds true l-positions lperm(pos4)+{0..3}; the
    // needed 1/li values live in lanes lperm(pos4)+j (all lanes have li).
    const float rli = 1.f / li;
    const int pos4 = (l & 7) * 4;
    const int lb = lperm(pos4);
    float sf[4];
#pragma unroll
    for (int j = 0; j < 4; ++j)
      sf[j] = __int_as_float(
          __builtin_amdgcn_ds_bpermute(4 * (lb + j), __float_as_int(rli)));
    __bf16* krow = kscale_t + ((size_t)bh * Z + (l >> 3)) * L + q0 + pos4;
#pragma unroll
    for (int pass = 0; pass < 8; ++pass) {
      union { __bf16 hh[4]; uint2 u; } v;
      v.u = *(uint2*)krow;
      v.hh[0] = (__bf16)((float)v.hh[0] * sf[0]);
      v.hh[1] = (__bf16)((float)v.hh[1] * sf[1]);
      v.hh[2] = (__bf16)((float)v.hh[2] * sf[2]);
      v.hh[3] = (__bf16)((float)v.hh[3] * sf[3]);
      *(uint2*)krow = v.u;
      krow += (size_t)8 * L;
    }
  }
}

// ---------------------------------------------------------------------------
// gx + energy fused: blocks 0..511 compute gx[m][d] = sum_hz Gkp*Wk + Gqp*Wq
// (64x128 tile, 2/CU, XCD-aware m-slab decode, triple-buffer + counted
// vmcnt -- R8's proven structure); blocks 512..513 compute
// en[b] = -(1/beta) * sum_{h,q} lse[b,h,q] (lse ready: grad<0> precedes).
// R15 fix: energy uses all 4 waves + float4 loads (R14's 1-wave scalar
// version was a ~120us serial tail at 2 waves chip-wide -> Occupancy 5.6%,
// gx dispatch 167us), and its cross-wave combine ALIASES gx's staging LDS
// (sA) so static LDS stays exactly 73728 B -- R13 measured that 73728x2 =
// 147456 is the exact 2-blocks/CU limit; +512B drops gx to 1 block/CU.
// ---------------------------------------------------------------------------
__global__ __launch_bounds__(256, 2) void gx_kernel(
    const __bf16* __restrict__ Gkp, const __bf16* __restrict__ Gqp,
    const __bf16* __restrict__ Wkt, const __bf16* __restrict__ Wqt,
    const float* __restrict__ lse_ws, const float* __restrict__ beta_p,
    float* __restrict__ out) {
  __shared__ __align__(16) char sA[3][8192], sB[3][16384];
  const int bid = blockIdx.x;                  // 0..513
  if (bid >= 512) {                            // ---- energy path
    const int b = bid - 512;
    const float4* p = (const float4*)(lse_ws + (size_t)b * H * L);
    float sum = 0.f;
    for (int i = threadIdx.x; i < (H * L) / 4; i += 256) {
      float4 v = p[i];
      sum += (v.x + v.y) + (v.z + v.w);
    }
#pragma unroll
    for (int off = 1; off < 64; off <<= 1) sum += __shfl_xor(sum, off, 64);
    float* wsum = (float*)sA;                  // alias staging LDS (unused here)
    if ((threadIdx.x & 63) == 0) wsum[threadIdx.x >> 6] = sum;
    __syncthreads();
    if (threadIdx.x == 0)
      out[b] = -(wsum[0] + wsum[1] + wsum[2] + wsum[3]) / beta_p[0];
    return;
  }
  float* __restrict__ gx = out + 2;
  const int xcd = bid & 7;                     // dispatch round-robin -> XCD
  const int nt_ = (bid >> 3) & 7;              // 8 n-tiles of 128
  const int mg = bid >> 6;                     // 8 m-tiles within the group
  const int m0 = (xcd * 8 + mg) * 64;          // XCD-local 512-row A-slab
  const int n0 = nt_ * 128;
  const int tid = threadIdx.x, l = tid & 63, w = tid >> 6;
  const int l31 = l & 31, hi = l >> 5;
  const int mh = w >> 1, nh = w & 1;           // 2 m-halves x 2 n-halves

  f32x16 acc[2];
#pragma unroll
  for (int ni = 0; ni < 2; ++ni)
#pragma unroll
    for (int i = 0; i < 16; ++i) acc[ni][i] = 0.f;

  // K-tile source helper: kk in [0,32), first 16 from Gkp/Wkt, rest Gqp/Wqt
  auto stageK = [&](int kn, char* a, char* b) {
    const __bf16* __restrict__ An = (kn < 16 ? Gkp : Gqp);
    const __bf16* __restrict__ Bn = (kn < 16 ? Wkt : Wqt);
    const int k0 = (kn & 15) * 64;
    stage_async<2>(An + (size_t)m0 * HZ + k0, HZ, a, tid);
    stage_async<4>(Bn + (size_t)n0 * HZ + k0, HZ, b, tid);
  };

  // prologue: tiles 0 and 1 (12 DMAs); wait tile 0 only (oldest 6).
  stageK(0, sA[0], sB[0]);
  stageK(1, sA[1], sB[1]);
  asm volatile("s_waitcnt vmcnt(6)" ::: "memory");
  __builtin_amdgcn_s_barrier();

  const char* a0 = sA[0]; const char* a1 = sA[1]; char* a2 = sA[2];
  const char* b0 = sB[0]; const char* b1 = sB[1]; char* b2 = sB[2];

  for (int kk = 0; kk < 32; ++kk) {
    // DMA tile kk+2 into the buffers freed at the end of iter kk-1
    if (kk < 30) stageK(kk + 2, a2, b2);
#pragma unroll
    for (int ks = 0; ks < 4; ++ks) {
      bf16x8 am, bn[2];
      am = rfrag(a0, mh * 32 + l31, 2 * ks + hi);
#pragma unroll
      for (int ni = 0; ni < 2; ++ni)
        bn[ni] = rfrag(b0, nh * 64 + ni * 32 + l31, 2 * ks + hi);
      __builtin_amdgcn_s_setprio(1);
#pragma unroll
      for (int ni = 0; ni < 2; ++ni)
        acc[ni] = __builtin_amdgcn_mfma_f32_32x32x16_bf16(
            am, bn[ni], acc[ni], 0, 0, 0);
      __builtin_amdgcn_s_setprio(0);
    }
    // counted-vmcnt barrier: wait ONLY the previous iteration's 6 DMAs
    if (kk < 30) {
      asm volatile("s_waitcnt vmcnt(6)" ::: "memory");
      __builtin_amdgcn_s_barrier();
    } else if (kk == 30) {
      asm volatile("s_waitcnt vmcnt(0)" ::: "memory");
      __builtin_amdgcn_s_barrier();
    }
    const char* x;
    x = a0; a0 = a1; a1 = a2; a2 = (char*)x;
    x = b0; b0 = b1; b1 = b2; b2 = (char*)x;
  }
#pragma unroll
  for (int ni = 0; ni < 2; ++ni) {
    const int n = n0 + nh * 64 + ni * 32 + l31;
#pragma unroll
    for (int r = 0; r < 16; ++r) {
      const int m = m0 + mh * 32 + (r & 3) + 8 * (r >> 2) + 4 * hi;
      gx[(size_t)m * D + n] = acc[ni][r];
    }
  }
}

// ---------------------------------------------------------------------------
extern "C" void kernel_launch(void* const* d_in, const int* in_sizes, int n_in,
                              void* d_out, int out_size, void* d_ws, size_t ws_size,
                              hipStream_t stream) {
  const float* x    = (const float*)d_in[0];
  const float* Wq   = (const float*)d_in[1];
  const float* Wk   = (const float*)d_in[2];
  const float* beta = (const float*)d_in[3];
  float* out = (float*)d_out;

  char* ws = (char*)d_ws;
  __bf16* xb  = (__bf16*)(ws);                         // 8 MB
  __bf16* Wkb = (__bf16*)(ws + (8ull  << 20));         // 2 MB
  __bf16* Wqb = (__bf16*)(ws + (10ull << 20));         // 2 MB
  __bf16* Wkt = (__bf16*)(ws + (12ull << 20));         // 2 MB
  __bf16* Wqt = (__bf16*)(ws + (14ull << 20));         // 2 MB
  __bf16* kp  = (__bf16*)(ws + (16ull << 20));         // 8 MB (scaled)
  __bf16* qp  = (__bf16*)(ws + (24ull << 20));         // 8 MB (scaled)
  __bf16* kpt = (__bf16*)(ws + (32ull << 20));         // 8 MB (l-perm, unscaled)
  __bf16* qpt = (__bf16*)(ws + (40ull << 20));         // 8 MB (l-perm, unscaled)
  __bf16* Gkp = (__bf16*)(ws + (48ull << 20));         // 8 MB
  __bf16* Gqp = (__bf16*)(ws + (56ull << 20));         // 8 MB
  float*  lse = (float*)(ws + (64ull << 20));          // 256 KB

  prep_kernel<<<4608, 256, 0, stream>>>(x, xb, Wk, Wq, Wkb, Wqb, Wkt, Wqt);
  proj_kernel<<<dim3(8, 32, 2), 256, 0, stream>>>(xb, Wkb, Wqb, beta, kp, qp, kpt, qpt);
  grad_kernel<0><<<512, 256, 0, stream>>>(kp, qp, qpt, lse, Gkp, kpt);
  grad_kernel<1><<<512, 256, 0, stream>>>(qp, kp, kpt, lse, Gqp, kpt);
  gx_kernel<<<514, 256, 0, stream>>>(Gkp, Gqp, Wkt, Wqt, lse, beta, out);
}

// Round 16
// 247.027 us; speedup vs baseline: 1.4608x; 1.0127x over previous
//
#include <hip/hip_runtime.h>
#include <math.h>

#define L 2048
#define D 1024
#define H 16
#define Z 64
#define HZ 1024

typedef __bf16 bf16x8 __attribute__((ext_vector_type(8)));
typedef float f32x4 __attribute__((ext_vector_type(4)));
typedef float f32x16 __attribute__((ext_vector_type(16)));

#if __has_builtin(__builtin_amdgcn_exp2f)
#define EXP2(x) __builtin_amdgcn_exp2f(x)
#else
#define EXP2(x) exp2f(x)
#endif

// ---------------------------------------------------------------------------
// Async global->LDS DMA, 16B per lane (lane i lands at base + i*16).
// ---------------------------------------------------------------------------
__device__ __forceinline__ void async_ld16(const void* g, void* l) {
  __builtin_amdgcn_global_load_lds(
      (const __attribute__((address_space(1))) uint32_t*)(uintptr_t)g,
      (__attribute__((address_space(3))) uint32_t*)(uint32_t)(uintptr_t)l,
      16, 0, 0);
}

// ---------------------------------------------------------------------------
// Fragment-ordered tile staging. 1KB region per (16-row group, 32-col half):
// region = (r>>4)*2 + (cc>>2), slot = (r&15) + (cc&3)*16  (cc = 16B chunk).
// ---------------------------------------------------------------------------
template<int NPIECE>
__device__ __forceinline__ void stage_async(const __bf16* __restrict__ g,
                                            int gstride, char* lds, int tid) {
  const int l = tid & 63, w = tid >> 6;
#pragma unroll
  for (int it = 0; it < NPIECE; ++it) {
    const int region = it * 4 + w;
    const int r = ((region >> 1) << 4) + (l & 15);
    const int c = ((region & 1) << 2) + (l >> 4);
    async_ld16(g + (size_t)r * gstride + c * 8, lds + (region << 10));
  }
}

__device__ __forceinline__ bf16x8 rfrag(const char* lds, int row, int cc) {
  const int region = ((row >> 4) << 1) + (cc >> 2);
  const int slot = (row & 15) + ((cc & 3) << 4);
  return *(const bf16x8*)(lds + region * 1024 + slot * 16);
}

// l-permutation for the transposed kp/qp buffers: within each 16-l group,
// 4-el pieces stored in order [0-3, 8-11, 4-7, 12-15].  (involution)
__device__ __forceinline__ int lperm(int mg) {
  const int off = mg & 15;
  return (mg & ~15) | (((off >> 2) & 1) << 3) | (((off >> 3) & 1) << 2);
}

// ---------------------------------------------------------------------------
// prep: fused cvt (fp32 x -> bf16 xb, blocks 0..4095) + wt (W -> Wb + Wt,
// blocks 4096..4607). Both are independent preprocessing; fusing saves a
// launch gap (R13 measured: launch fusion recovered ~29us total).
// ---------------------------------------------------------------------------
__global__ __launch_bounds__(256) void prep_kernel(
    const float* __restrict__ x, __bf16* __restrict__ xb,
    const float* __restrict__ Wk, const float* __restrict__ Wq,
    __bf16* __restrict__ Wkb, __bf16* __restrict__ Wqb,
    __bf16* __restrict__ Wkt, __bf16* __restrict__ Wqt) {
  __shared__ __bf16 tile[64][65];
  const int bid = blockIdx.x;
  if (bid < 4096) {                    // ---- cvt path (n4 = 4096*256 exact)
    int i = bid * 256 + threadIdx.x;
    float4 v = ((const float4*)x)[i];
    union { __bf16 h[4]; uint2 u; } o;
    o.h[0] = (__bf16)v.x; o.h[1] = (__bf16)v.y;
    o.h[2] = (__bf16)v.z; o.h[3] = (__bf16)v.w;
    ((uint2*)xb)[i] = o.u;
    return;
  }
  const int wb = bid - 4096;           // ---- wt path: 512 blocks
  const int bz = wb >> 8, rem = wb & 255, by = rem >> 4, bx = rem & 15;
  const float* W = bz ? Wq : Wk;
  __bf16* Wb = bz ? Wqb : Wkb;
  __bf16* Wt = bz ? Wqt : Wkt;
  const int r0 = by * 64, c0 = bx * 64;
  const int c = threadIdx.x & 63, rb = threadIdx.x >> 6;
#pragma unroll
  for (int i = 0; i < 16; ++i) {
    int r = rb + i * 4;
    __bf16 v = (__bf16)W[(size_t)(r0 + r) * D + c0 + c];
    tile[r][c] = v;
    Wb[(size_t)(r0 + r) * D + c0 + c] = v;
  }
  __syncthreads();
#pragma unroll
  for (int i = 0; i < 16; ++i) {
    int r = rb + i * 4;
    Wt[(size_t)(c0 + r) * HZ + r0 + c] = tile[c][r];
  }
}

// ---------------------------------------------------------------------------
// proj (R10-proven): kp/qp[bh][l][z] = SCALE * sum_d x*W  (SCALE =
// sqrt(beta*log2e) so grad's S-MFMAs produce log2-domain scores directly);
// kpt/qpt[bh][z][l] = UNSCALED (l-permuted) -> PV operands.
// 128x128 tile, 4 waves x 64x64 quadrant, 32x32x16 MFMA, BK=64,
// async-DMA double-buffered LDS, single barrier per K-iter.
// ---------------------------------------------------------------------------
__global__ __launch_bounds__(256, 2) void proj_kernel(
    const __bf16* __restrict__ xb, const __bf16* __restrict__ Wkb,
    const __bf16* __restrict__ Wqb, const float* __restrict__ beta_p,
    __bf16* __restrict__ kp, __bf16* __restrict__ qp,
    __bf16* __restrict__ kpt, __bf16* __restrict__ qpt) {
  const __bf16* __restrict__ Wb = blockIdx.z ? Wqb : Wkb;
  __bf16* __restrict__ outn = blockIdx.z ? qp : kp;
  __bf16* __restrict__ outt = blockIdx.z ? qpt : kpt;
  const int n0 = blockIdx.x * 128, m0 = blockIdx.y * 128;
  const int tid = threadIdx.x, l = tid & 63, w = tid >> 6;
  const int l31 = l & 31, hi = l >> 5;
  const int mh = w >> 1, nh = w & 1;
  const float ab = beta_p[0] * 1.44269504f;
  const float ssc = sqrtf(fabsf(ab));
  const float sc = blockIdx.z ? ssc : ((ab < 0.f) ? -ssc : ssc);
  __shared__ __align__(16) char sA[2][16384], sB[2][16384];

  f32x16 acc[2][2];
#pragma unroll
  for (int mi = 0; mi < 2; ++mi)
#pragma unroll
    for (int ni = 0; ni < 2; ++ni)
#pragma unroll
      for (int i = 0; i < 16; ++i) acc[mi][ni][i] = 0.f;

  const __bf16* __restrict__ Abase = xb + (size_t)m0 * D;
  const __bf16* __restrict__ Bbase = Wb + (size_t)n0 * D;
  stage_async<4>(Abase, D, sA[0], tid);
  stage_async<4>(Bbase, D, sB[0], tid);
  __syncthreads();

  for (int k = 0; k < 16; ++k) {
    const int cur = k & 1, nxt = cur ^ 1;
    if (k < 15) {
      stage_async<4>(Abase + (k + 1) * 64, D, sA[nxt], tid);
      stage_async<4>(Bbase + (k + 1) * 64, D, sB[nxt], tid);
    }
#pragma unroll
    for (int ks = 0; ks < 4; ++ks) {
      bf16x8 am[2], bn[2];
#pragma unroll
      for (int mi = 0; mi < 2; ++mi)
        am[mi] = rfrag(sA[cur], mh * 64 + mi * 32 + l31, 2 * ks + hi);
#pragma unroll
      for (int ni = 0; ni < 2; ++ni)
        bn[ni] = rfrag(sB[cur], nh * 64 + ni * 32 + l31, 2 * ks + hi);
#pragma unroll
      for (int mi = 0; mi < 2; ++mi)
#pragma unroll
        for (int ni = 0; ni < 2; ++ni)
          acc[mi][ni] = __builtin_amdgcn_mfma_f32_32x32x16_bf16(
              am[mi], bn[ni], acc[mi][ni], 0, 0, 0);
    }
    __syncthreads();
  }

  const int b = m0 >> 11;
  const int h = (n0 >> 6) + nh;
  const size_t bh = (size_t)b * H + h;
#pragma unroll
  for (int mi = 0; mi < 2; ++mi)
#pragma unroll
    for (int ni = 0; ni < 2; ++ni) {
      const int z = ni * 32 + l31;
#pragma unroll
      for (int rg = 0; rg < 4; ++rg) {
        const int mloc = mh * 64 + mi * 32 + 8 * rg + 4 * hi;
        const int mg = (m0 & (L - 1)) + mloc;
        union { __bf16 hh[4]; uint2 u; } pk;
#pragma unroll
        for (int j = 0; j < 4; ++j) {
          const float v = acc[mi][ni][4 * rg + j];
          pk.hh[j] = (__bf16)v;                                 // unscaled -> T
          outn[(bh * L + mg + j) * Z + z] = (__bf16)(v * sc);   // scaled -> S ops
        }
        *(uint2*)(outt + (bh * Z + z) * L + lperm(mg)) = pk.u;
      }
    }
}

// ---------------------------------------------------------------------------
// grad kernel (R10, proven): 32x32x16 MFMA, 1 q-tile (32 rows) per wave,
// 512-block x 4-wave shape. BOTH S and T tiles staged through LDS (R6)
// with triple-buffer + counted-vmcnt barriers (T3/T4). R9/R11 q=64
// widening spilled both times (VGPR pinned at 128) -- do not widen.
// kscale FUSED into the MODE-0 epilogue (R10).
// Scores come out of the S-MFMA already in log2-domain (inputs pre-scaled).
// MODE 0: Gkp[q][z] = -(1/li_q) sum_c 2^S[q][c] * qp[c][z]; lse=ln(li);
//         then kpt *= 1/li along its q-columns.
// MODE 1: Gqp[kq][z] = -sum_q 2^S[q][kq] * kpw[q][z]  (kpw pre-scaled)
// ---------------------------------------------------------------------------
template<int MODE>
__global__ __launch_bounds__(256, 2) void grad_kernel(
    const __bf16* __restrict__ Rg, const __bf16* __restrict__ Sg,
    const __bf16* __restrict__ Tg,
    float* __restrict__ lse, __bf16* __restrict__ Gout,
    __bf16* __restrict__ kscale_t) {
  const int bid = blockIdx.x;
  const int slot = bid >> 3;
  const int bh = (bid & 7) * 4 + (slot >> 4);
  const int qt = slot & 15;
  const int tid = threadIdx.x, l = tid & 63, w = tid >> 6;
  const int l31 = l & 31, hi = l >> 5;
  const int q0 = qt * 128 + w * 32;
  __shared__ __align__(16) char sS[3][8192], sT[3][8192];  // triple-buffered

  // resident operand as 32x32x16 B-fragments: B[n=l31][k=16ks+8hi+j]
  bf16x8 bres[4];
#pragma unroll
  for (int ks = 0; ks < 4; ++ks)
    bres[ks] = *(const bf16x8*)(
        Rg + ((size_t)bh * L + q0 + l31) * Z + ks * 16 + hi * 8);

  f32x16 pv[2];
#pragma unroll
  for (int zt = 0; zt < 2; ++zt)
#pragma unroll
    for (int i = 0; i < 16; ++i) pv[zt][i] = 0.f;
  float li = 0.f;

  const __bf16* __restrict__ Sbase = Sg + (size_t)bh * L * Z;  // + c*Z
  const __bf16* __restrict__ Tbase = Tg + (size_t)bh * Z * L;  // + z*L + c

  // prologue: bres(4) then tiles 0 and 1 for both S and T (8 DMAs).
  // vmcnt(4) waits bres + tile0 (oldest 8), leaves tile1's 4 in flight.
  stage_async<2>(Sbase, Z, sS[0], tid);
  stage_async<2>(Tbase, L, sT[0], tid);
  stage_async<2>(Sbase + (size_t)64 * Z, Z, sS[1], tid);
  stage_async<2>(Tbase + 64, L, sT[1], tid);
  asm volatile("s_waitcnt vmcnt(4)" ::: "memory");
  __builtin_amdgcn_s_barrier();

  const char* s0 = sS[0]; const char* s1 = sS[1]; char* s2 = sS[2];
  const char* t0 = sT[0]; const char* t1 = sT[1]; char* t2 = sT[2];

  for (int kt = 0; kt < 32; ++kt) {
    // fragments for the current tile (DMA'd >= 1 full iteration ago)
    bf16x8 av[8], bt[8];
#pragma unroll
    for (int ks = 0; ks < 4; ++ks) {
      av[ks]     = rfrag(s0, l31,      2 * ks + hi);
      av[4 + ks] = rfrag(s0, 32 + l31, 2 * ks + hi);
      bt[2 * ks]     = rfrag(t0, l31,      2 * ks + hi);
      bt[2 * ks + 1] = rfrag(t0, 32 + l31, 2 * ks + hi);
    }
    // DMA tile kt+2 into the buffers freed at the end of iter kt-1
    if (kt < 30) {
      stage_async<2>(Sbase + (size_t)(kt + 2) * 64 * Z, Z, s2, tid);
      stage_async<2>(Tbase + (kt + 2) * 64, L, t2, tid);
    }
    // St[c][q] = sum_z streamed[c][z] * resident[q][z]  (log2-domain scores)
    f32x16 st[2];
#pragma unroll
    for (int i = 0; i < 16; ++i) { st[0][i] = 0.f; st[1][i] = 0.f; }
    __builtin_amdgcn_s_setprio(1);
#pragma unroll
    for (int ks = 0; ks < 4; ++ks) {
      st[0] = __builtin_amdgcn_mfma_f32_32x32x16_bf16(av[ks], bres[ks], st[0], 0, 0, 0);
      st[1] = __builtin_amdgcn_mfma_f32_32x32x16_bf16(av[4 + ks], bres[ks], st[1], 0, 0, 0);
    }
    __builtin_amdgcn_s_setprio(0);
    // P = 2^St (fixed max = 0), packed as PV A-frags
    uint32_t P32[2][8];
    float lsn = 0.f;
#pragma unroll
    for (int nt = 0; nt < 2; ++nt)
#pragma unroll
      for (int i = 0; i < 8; ++i) {
        float e0 = EXP2(st[nt][2 * i]);
        float e1 = EXP2(st[nt][2 * i + 1]);
        if (MODE == 0) lsn += e0 + e1;
        union { __bf16 hh[2]; uint32_t u; } pk;
        pk.hh[0] = (__bf16)e0; pk.hh[1] = (__bf16)e1;
        P32[nt][i] = pk.u;
      }
    if (MODE == 0) li += lsn;
    // PV: D[q][z] += P[q][c] * T[c][z]
    __builtin_amdgcn_s_setprio(1);
#pragma unroll
    for (int kc = 0; kc < 4; ++kc) {
      union { uint32_t u[4]; bf16x8 v; } a;
#pragma unroll
      for (int i = 0; i < 4; ++i) a.u[i] = P32[kc >> 1][4 * (kc & 1) + i];
      pv[0] = __builtin_amdgcn_mfma_f32_32x32x16_bf16(a.v, bt[2 * kc], pv[0], 0, 0, 0);
      pv[1] = __builtin_amdgcn_mfma_f32_32x32x16_bf16(a.v, bt[2 * kc + 1], pv[1], 0, 0, 0);
    }
    __builtin_amdgcn_s_setprio(0);
    // counted-vmcnt barrier: wait ONLY the previous iteration's 4 DMAs
    // (outstanding = prev 4 + this iter's 4 = 8 -> vmcnt(4)).
    if (kt < 30) {
      asm volatile("s_waitcnt vmcnt(4)" ::: "memory");
      __builtin_amdgcn_s_barrier();
    } else if (kt == 30) {           // nothing issued this iter: wait last 4
      asm volatile("s_waitcnt vmcnt(0)" ::: "memory");
      __builtin_amdgcn_s_barrier();
    }                                // kt==31: nothing left to stage
    const char* x;
    x = s0; s0 = s1; s1 = s2; s2 = (char*)x;
    x = t0; t0 = t1; t1 = t2; t2 = (char*)x;
  }

  if (MODE == 0) li += __shfl_xor(li, 32);
  const int b = bh >> 4, head = bh & (H - 1);
#pragma unroll
  for (int r = 0; r < 16; ++r) {
    const int qoff = (r & 3) + 8 * (r >> 2) + 4 * hi;   // C-layout row
    float scl = 1.f;
    if (MODE == 0)
      scl = 1.f / __int_as_float(
                __builtin_amdgcn_ds_bpermute(4 * qoff, __float_as_int(li)));
    const size_t orow = ((size_t)b * L + q0 + qoff) * HZ + head * Z;
    Gout[orow + l31]      = (__bf16)(-pv[0][r] * scl);
    Gout[orow + 32 + l31] = (__bf16)(-pv[1][r] * scl);
  }
  if (MODE == 0) {
    if (hi == 0)
      lse[(size_t)bh * L + q0 + l31] = __logf(li);
    // ---- fused kscale: kpt[bh][z][q0..q0+32) *= 1/li (this wave's q-range).
    // lane l: piece = l&7 (4 stored bf16 at offset 4*piece), z = l>>3 (+8/pass).
    // Stored piece at pos4 holds true l-positions lperm(pos4)+{0..3}; the
    // needed 1/li values live in lanes lperm(pos4)+j (all lanes have li).
    const float rli = 1.f / li;
    const int pos4 = (l & 7) * 4;
    const int lb = lperm(pos4);
    float sf[4];
#pragma unroll
    for (int j = 0; j < 4; ++j)
      sf[j] = __int_as_float(
          __builtin_amdgcn_ds_bpermute(4 * (lb + j), __float_as_int(rli)));
    __bf16* krow = kscale_t + ((size_t)bh * Z + (l >> 3)) * L + q0 + pos4;
#pragma unroll
    for (int pass = 0; pass < 8; ++pass) {
      union { __bf16 hh[4]; uint2 u; } v;
      v.u = *(uint2*)krow;
      v.hh[0] = (__bf16)((float)v.hh[0] * sf[0]);
      v.hh[1] = (__bf16)((float)v.hh[1] * sf[1]);
      v.hh[2] = (__bf16)((float)v.hh[2] * sf[2]);
      v.hh[3] = (__bf16)((float)v.hh[3] * sf[3]);
      *(uint2*)krow = v.u;
      krow += (size_t)8 * L;
    }
  }
}

// ---------------------------------------------------------------------------
// gx + energy fused. R16: 3 blocks/CU -- double-buffered LDS (48KB; 3x49152
// = 147456 = the exact per-CU budget measured in R13) + __launch_bounds__
// (256,3) (170-reg cap >> ~120 used, no spill). Two effects: (1) all 514
// blocks are first-round resident (R15: blocks 512/513 waited for a gx
// block to retire -> ~5us tail, gx 51->56us); (2) the full-drain barrier
// (R7-style double-buffer) now has TWO partner blocks per CU covering it.
// Blocks 0..511: gx[m][d] = sum_hz Gkp*Wk + Gqp*Wq (64x128 tile, XCD-aware
// m-slab decode). Blocks 512..513: en[b] (4 waves, float4, LDS aliased).
// ---------------------------------------------------------------------------
__global__ __launch_bounds__(256, 3) void gx_kernel(
    const __bf16* __restrict__ Gkp, const __bf16* __restrict__ Gqp,
    const __bf16* __restrict__ Wkt, const __bf16* __restrict__ Wqt,
    const float* __restrict__ lse_ws, const float* __restrict__ beta_p,
    float* __restrict__ out) {
  __shared__ __align__(16) char sA[2][8192], sB[2][16384];
  const int bid = blockIdx.x;                  // 0..513
  if (bid >= 512) {                            // ---- energy path
    const int b = bid - 512;
    const float4* p = (const float4*)(lse_ws + (size_t)b * H * L);
    float sum = 0.f;
    for (int i = threadIdx.x; i < (H * L) / 4; i += 256) {
      float4 v = p[i];
      sum += (v.x + v.y) + (v.z + v.w);
    }
#pragma unroll
    for (int off = 1; off < 64; off <<= 1) sum += __shfl_xor(sum, off, 64);
    float* wsum = (float*)sA;                  // alias staging LDS (unused here)
    if ((threadIdx.x & 63) == 0) wsum[threadIdx.x >> 6] = sum;
    __syncthreads();
    if (threadIdx.x == 0)
      out[b] = -(wsum[0] + wsum[1] + wsum[2] + wsum[3]) / beta_p[0];
    return;
  }
  float* __restrict__ gx = out + 2;
  const int xcd = bid & 7;                     // dispatch round-robin -> XCD
  const int nt_ = (bid >> 3) & 7;              // 8 n-tiles of 128
  const int mg = bid >> 6;                     // 8 m-tiles within the group
  const int m0 = (xcd * 8 + mg) * 64;          // XCD-local 512-row A-slab
  const int n0 = nt_ * 128;
  const int tid = threadIdx.x, l = tid & 63, w = tid >> 6;
  const int l31 = l & 31, hi = l >> 5;
  const int mh = w >> 1, nh = w & 1;           // 2 m-halves x 2 n-halves

  f32x16 acc[2];
#pragma unroll
  for (int ni = 0; ni < 2; ++ni)
#pragma unroll
    for (int i = 0; i < 16; ++i) acc[ni][i] = 0.f;

  // K-tile source helper: kk in [0,32), first 16 from Gkp/Wkt, rest Gqp/Wqt
  auto stageK = [&](int kn, char* a, char* b) {
    const __bf16* __restrict__ An = (kn < 16 ? Gkp : Gqp);
    const __bf16* __restrict__ Bn = (kn < 16 ? Wkt : Wqt);
    const int k0 = (kn & 15) * 64;
    stage_async<2>(An + (size_t)m0 * HZ + k0, HZ, a, tid);
    stage_async<4>(Bn + (size_t)n0 * HZ + k0, HZ, b, tid);
  };

  stageK(0, sA[0], sB[0]);
  __syncthreads();

  for (int kk = 0; kk < 32; ++kk) {
    const int cur = kk & 1, nxt = cur ^ 1;
    if (kk < 31) stageK(kk + 1, sA[nxt], sB[nxt]);
#pragma unroll
    for (int ks = 0; ks < 4; ++ks) {
      bf16x8 am, bn[2];
      am = rfrag(sA[cur], mh * 32 + l31, 2 * ks + hi);
#pragma unroll
      for (int ni = 0; ni < 2; ++ni)
        bn[ni] = rfrag(sB[cur], nh * 64 + ni * 32 + l31, 2 * ks + hi);
      __builtin_amdgcn_s_setprio(1);
#pragma unroll
      for (int ni = 0; ni < 2; ++ni)
        acc[ni] = __builtin_amdgcn_mfma_f32_32x32x16_bf16(
            am, bn[ni], acc[ni], 0, 0, 0);
      __builtin_amdgcn_s_setprio(0);
    }
    __syncthreads();
  }
#pragma unroll
  for (int ni = 0; ni < 2; ++ni) {
    const int n = n0 + nh * 64 + ni * 32 + l31;
#pragma unroll
    for (int r = 0; r < 16; ++r) {
      const int m = m0 + mh * 32 + (r & 3) + 8 * (r >> 2) + 4 * hi;
      gx[(size_t)m * D + n] = acc[ni][r];
    }
  }
}

// ---------------------------------------------------------------------------
extern "C" void kernel_launch(void* const* d_in, const int* in_sizes, int n_in,
                              void* d_out, int out_size, void* d_ws, size_t ws_size,
                              hipStream_t stream) {
  const float* x    = (const float*)d_in[0];
  const float* Wq   = (const float*)d_in[1];
  const float* Wk   = (const float*)d_in[2];
  const float* beta = (const float*)d_in[3];
  float* out = (float*)d_out;

  char* ws = (char*)d_ws;
  __bf16* xb  = (__bf16*)(ws);                         // 8 MB
  __bf16* Wkb = (__bf16*)(ws + (8ull  << 20));         // 2 MB
  __bf16* Wqb = (__bf16*)(ws + (10ull << 20));         // 2 MB
  __bf16* Wkt = (__bf16*)(ws + (12ull << 20));         // 2 MB
  __bf16* Wqt = (__bf16*)(ws + (14ull << 20));         // 2 MB
  __bf16* kp  = (__bf16*)(ws + (16ull << 20));         // 8 MB (scaled)
  __bf16* qp  = (__bf16*)(ws + (24ull << 20));         // 8 MB (scaled)
  __bf16* kpt = (__bf16*)(ws + (32ull << 20));         // 8 MB (l-perm, unscaled)
  __bf16* qpt = (__bf16*)(ws + (40ull << 20));         // 8 MB (l-perm, unscaled)
  __bf16* Gkp = (__bf16*)(ws + (48ull << 20));         // 8 MB
  __bf16* Gqp = (__bf16*)(ws + (56ull << 20));         // 8 MB
  float*  lse = (float*)(ws + (64ull << 20));          // 256 KB

  prep_kernel<<<4608, 256, 0, stream>>>(x, xb, Wk, Wq, Wkb, Wqb, Wkt, Wqt);
  proj_kernel<<<dim3(8, 32, 2), 256, 0, stream>>>(xb, Wkb, Wqb, beta, kp, qp, kpt, qpt);
  grad_kernel<0><<<512, 256, 0, stream>>>(kp, qp, qpt, lse, Gkp, kpt);
  grad_kernel<1><<<512, 256, 0, stream>>>(qp, kp, kpt, lse, Gqp, kpt);
  gx_kernel<<<514, 256, 0, stream>>>(Gkp, Gqp, Wkt, Wqt, lse, beta, out);
}